// Round 10
// baseline (5419.295 us; speedup 1.0000x reference)
//
#include <hip/hip_runtime.h>
#include <hip/hip_bf16.h>
#include <stdint.h>

#define Bsz 1024
#define Tt  100
#define Pp  50
#define Ii  96
#define Hh  1024
#define H3  3072

typedef __bf16 bf16x8 __attribute__((ext_vector_type(8)));
typedef float f32x4 __attribute__((ext_vector_type(4)));
typedef __hip_bfloat16 bf16;

__device__ __forceinline__ void llds16(const void* g, void* l) {
    __builtin_amdgcn_global_load_lds(
        (const __attribute__((address_space(1))) void*)g,
        (__attribute__((address_space(3))) void*)l,
        16, 0, 0);
}

// bf16x4 (as ushort4) -> f32x4, exact
__device__ __forceinline__ f32x4 ldb4(const bf16* p) {
    ushort4 u = *(const ushort4*)p;
    union { unsigned int i; float f; } c;
    f32x4 r;
    c.i = (unsigned int)u.x << 16; r[0] = c.f;
    c.i = (unsigned int)u.y << 16; r[1] = c.f;
    c.i = (unsigned int)u.z << 16; r[2] = c.f;
    c.i = (unsigned int)u.w << 16; r[3] = c.f;
    return r;
}

__device__ __forceinline__ float b2f(bf16 v) {
    union { unsigned int i; float f; } c;
    c.i = (unsigned int)(*(unsigned short*)&v) << 16;
    return c.f;
}

__device__ __forceinline__ void swz_decomp(int& bx, int& by, int& bz) {
    int gx = gridDim.x, gy = gridDim.y, gz = gridDim.z;
    int flat = blockIdx.x + gx * (blockIdx.y + gy * blockIdx.z);
    int tot = gx * gy * gz;
    if (!(tot & 7)) {
        int q = tot >> 3;
        flat = (flat & 7) * q + (flat >> 3);
    }
    bx = flat % gx;
    int rest = flat / gx;
    by = rest % gy;
    bz = rest / gy;
}

// descriptor slot writer: slot = {A, W, bias, C, K, lda, 0, 0}
__global__ void wdesc_k(unsigned long long* slot, const void* A, const void* W,
                        const void* b, void* C, int K, int lda) {
    if (threadIdx.x == 0) {
        slot[0] = (unsigned long long)A;
        slot[1] = (unsigned long long)W;
        slot[2] = (unsigned long long)b;
        slot[3] = (unsigned long long)C;
        slot[4] = (unsigned long long)K;
        slot[5] = (unsigned long long)lda;
    }
}

// Batched GEMM from descriptor table, BK=64, XOR-swizzled LDS.
// Descriptor g (of ndesc) owns 192 blocks (24 N-tiles x 8 M-tiles):
// C[1024x3072](bf16) = A[1024xK(lda)] @ W[3072xK]^T + bias.  K % 64 == 0.
// Slot with A==0 uses extraA. grid = ndesc*192 (1-D).
__global__ void __launch_bounds__(256)
gemm_tab(const unsigned long long* __restrict__ tab, int base, int ndesc,
         const bf16* __restrict__ extraA)
{
    __shared__ bf16 As[128 * 64];
    __shared__ bf16 Ws[128 * 64];
    int flat = blockIdx.x;
    const int tot = ndesc * 192;
    if (!(tot & 7)) {
        int q = tot >> 3;
        flat = (flat & 7) * q + (flat >> 3);
    }
    const int g = flat / 192;
    const int local = flat - g * 192;
    const unsigned long long* dp = tab + (size_t)(base + g) * 8;
    const bf16* A = (const bf16*)dp[0];
    const bf16* W = (const bf16*)dp[1];
    const float* bias = (const float*)dp[2];
    bf16* C = (bf16*)dp[3];
    const int K = (int)dp[4];
    const int lda = (int)dp[5];
    if (!A) A = extraA;

    const int tn = (local % 24) * 128;
    const int tm = (local / 24) * 128;

    const int tid = threadIdx.x;
    const int lane = tid & 63;
    const int wid = tid >> 6;              // 4 waves: 2x2 of 64x64
    const int wr = (wid >> 1) * 64;
    const int wc = (wid & 1) * 64;
    const int srow = tid >> 3;             // 0..31 (8 threads x 16B per 128B row)
    const int schk = ((tid & 7) ^ (srow & 7)) * 8;  // swizzled global chunk (elems)
    const int sdst = tid * 16;             // linear LDS byte offset (lane-linear)
    const int fr = lane & 15;
    const int hi = lane >> 4;

    f32x4 acc[4][4] = {};

    const bf16* ga = A + (size_t)(tm + srow) * lda + schk;
    const bf16* gw = W + (size_t)(tn + srow) * K + schk;
    char* lA = (char*)As + sdst;
    char* lW = (char*)Ws + sdst;
    const int nk = K >> 6;

    for (int kt = 0; kt < nk; ++kt) {
#pragma unroll
        for (int m = 0; m < 4; ++m) {
            llds16(ga + (size_t)(32 * m) * lda, lA + 32 * m * 128);
            llds16(gw + (size_t)(32 * m) * K,  lW + 32 * m * 128);
        }
        ga += 64; gw += 64;
        __syncthreads();

#pragma unroll
        for (int kk = 0; kk < 2; ++kk) {
            bf16x8 af[4], wf[4];
            const int chk = (((kk << 2) + hi) ^ (fr & 7)) * 8;
#pragma unroll
            for (int i = 0; i < 4; ++i) {
                af[i] = *(const bf16x8*)&As[(wr + i * 16 + fr) * 64 + chk];
                wf[i] = *(const bf16x8*)&Ws[(wc + i * 16 + fr) * 64 + chk];
            }
#pragma unroll
            for (int mi = 0; mi < 4; ++mi)
#pragma unroll
                for (int ni = 0; ni < 4; ++ni)
                    acc[mi][ni] = __builtin_amdgcn_mfma_f32_16x16x32_bf16(
                        af[mi], wf[ni], acc[mi][ni], 0, 0, 0);
        }
        __syncthreads();
    }

    const int fq = hi * 4;
#pragma unroll
    for (int mi = 0; mi < 4; ++mi)
#pragma unroll
        for (int ni = 0; ni < 4; ++ni) {
            const int col = tn + wc + ni * 16 + fr;
            const float bv = bias[col];
#pragma unroll
            for (int r = 0; r < 4; ++r) {
                const int row = tm + wr + mi * 16 + fq + r;
                C[(size_t)row * H3 + col] = __float2bfloat16(acc[mi][ni][r] + bv);
            }
        }
}

// Fused decoder cell1 + fc_out GEMM. grid = 256: flat -> s(8 splitK) x tmi(16) x bx(2).
// Phase 1: GRU cell for rows [tm,tm+64) x h-cols [k0,k0+128) -> h1out/h1b global
//          (bx-duplicated identical writes) + bf16 A-tile in LDS.
// Phase 2: gemm64-style split-K MFMA vs wfcout -> gfc partial s (bias on s==0).
__global__ void __launch_bounds__(256)
cellfc_k(const bf16* __restrict__ gi, const bf16* __restrict__ gh,
         const float* __restrict__ hin, float* __restrict__ hout,
         bf16* __restrict__ hb,
         const bf16* __restrict__ W,      // wfcout [128][1024]
         const float* __restrict__ bias,  // fcout_b [96]
         float* __restrict__ gfc)         // [8][Bsz][Ii] partials
{
    __shared__ bf16 Af[64 * 136];         // +8 pad -> 2-way (free) on b128 reads
    __shared__ bf16 Ws[64 * 32];
    int flat = blockIdx.x;
    { int q = 256 >> 3; flat = (flat & 7) * q + (flat >> 3); }
    const int s = flat >> 5;
    const int rest = flat & 31;
    const int tm = (rest >> 1) * 64;
    const int tn = (rest & 1) * 64;
    const int k0 = s * 128;
    const int tid = threadIdx.x;

    // phase 1: cell, 64 rows x 128 cols = 2048 ushort4 items, 8/thread, coalesced
#pragma unroll
    for (int i = 0; i < 8; ++i) {
        int c = i * 256 + tid;
        int row = c >> 5;
        int c4 = (c & 31) * 4;
        int b = tm + row;
        int j = k0 + c4;
        size_t gbase = (size_t)b * H3 + j;
        f32x4 ir = ldb4(gi + gbase);
        f32x4 iz = ldb4(gi + gbase + Hh);
        f32x4 in = ldb4(gi + gbase + 2 * Hh);
        f32x4 hr = ldb4(gh + gbase);
        f32x4 hz = ldb4(gh + gbase + Hh);
        f32x4 hn = ldb4(gh + gbase + 2 * Hh);
        size_t ho = (size_t)b * Hh + j;
        f32x4 hold = *(const f32x4*)(hin + ho);
        f32x4 hv;
        ushort4 up;
        unsigned short* us = &up.x;
#pragma unroll
        for (int e = 0; e < 4; ++e) {
            float r = 1.f / (1.f + __expf(-(ir[e] + hr[e])));
            float z = 1.f / (1.f + __expf(-(iz[e] + hz[e])));
            float n = tanhf(in[e] + r * hn[e]);
            float v = (1.f - z) * n + z * hold[e];
            hv[e] = v;
            bf16 bv = __float2bfloat16(v);
            us[e] = *(unsigned short*)&bv;
        }
        *(f32x4*)(hout + ho) = hv;
        *(ushort4*)((unsigned short*)hb + ho) = up;
        *(ushort4*)&Af[row * 136 + c4] = up;
    }
    __syncthreads();

    // phase 2: gemm64 core, Ks=128 (nk=4), A from LDS Af
    const int lane = tid & 63;
    const int wid = tid >> 6;
    const int wr = (wid >> 1) * 32;
    const int wc = (wid & 1) * 32;
    const int srow = tid >> 2;
    const int skb = (tid & 3) * 8;
    const int fr = lane & 15;
    const int kg = (lane >> 4) * 8;

    f32x4 acc[2][2] = {};
    const bf16* gw = W + (size_t)(tn + srow) * Hh + k0 + skb;
    bf16* lW = &Ws[srow * 32 + skb];

    for (int kt = 0; kt < 4; ++kt) {
        llds16(gw, lW);
        gw += 32;
        __syncthreads();
        bf16x8 af[2], wf[2];
#pragma unroll
        for (int i = 0; i < 2; ++i) {
            af[i] = *(const bf16x8*)&Af[(wr + i * 16 + fr) * 136 + kt * 32 + kg];
            wf[i] = *(const bf16x8*)&Ws[(wc + i * 16 + fr) * 32 + kg];
        }
#pragma unroll
        for (int mi = 0; mi < 2; ++mi)
#pragma unroll
            for (int ni = 0; ni < 2; ++ni)
                acc[mi][ni] = __builtin_amdgcn_mfma_f32_16x16x32_bf16(
                    af[mi], wf[ni], acc[mi][ni], 0, 0, 0);
        __syncthreads();
    }

    float* Cf = gfc + (size_t)s * (Bsz * Ii);
    const int fq = (lane >> 4) * 4;
#pragma unroll
    for (int mi = 0; mi < 2; ++mi)
#pragma unroll
        for (int ni = 0; ni < 2; ++ni) {
            const int col = tn + wc + ni * 16 + fr;
            if (col < Ii) {
                const float bv = (s == 0) ? bias[col] : 0.f;
#pragma unroll
                for (int r = 0; r < 4; ++r) {
                    const int row = tm + wr + mi * 16 + fq + r;
                    Cf[(size_t)row * Ii + col] = acc[mi][ni][r] + bv;
                }
            }
        }
}

// Fused decoder tail: frame update + gi0 GEMM (vs Wcomb) + GRU cell0.
// grid = 128: flat -> tmi(16, 64 rows) x jt(8, 128 h-cols). 256 threads.
__global__ void __launch_bounds__(256)
megafuse_k(const float* __restrict__ gp,    // [8][Bsz][Ii] partials (bias in p0)
           const float* __restrict__ fin,   // frame in  [Bsz][Ii]
           float* __restrict__ fout,        // frame out [Bsz][Ii]
           float* __restrict__ out_t,       // out + (Pp+t)*Ii, row stride Tt*Ii
           const bf16* __restrict__ W,      // Wcomb [3072][128]
           const float* __restrict__ bias,  // bcomb [3072]
           const bf16* __restrict__ gh,     // gh0_p [Bsz][3072]
           float* __restrict__ h,           // h0 [Bsz][1024] (in-place)
           bf16* __restrict__ hb)           // h0b [Bsz][1024]
{
    __shared__ bf16 Af[64 * 136];
    __shared__ bf16 Ws[128 * 64];
    int flat = blockIdx.x;
    { int q = 128 >> 3; flat = (flat & 7) * q + (flat >> 3); }
    const int tm = (flat >> 3) * 64;
    const int jt = flat & 7;
    const int tid = threadIdx.x;

    // phase A: frame rows [tm,tm+64): 64*24 = 1536 f32x4, 6/thread, coalesced
#pragma unroll
    for (int i = 0; i < 6; ++i) {
        int v = i * 256 + tid;
        int row = v / 24;
        int c4 = (v % 24) * 4;
        size_t go = (size_t)(tm + row) * Ii + c4;
        f32x4 s = {};
#pragma unroll
        for (int p = 0; p < 8; ++p)
            s += *(const f32x4*)(gp + (size_t)p * (Bsz * Ii) + go);
        f32x4 fv = *(const f32x4*)(fin + go) + s;
        if (jt == 0) {
            *(f32x4*)(fout + go) = fv;
            *(f32x4*)(out_t + (size_t)(tm + row) * (Tt * Ii) + c4) = fv;
        }
        ushort4 up;
        unsigned short* us = &up.x;
#pragma unroll
        for (int e = 0; e < 4; ++e) {
            bf16 bv = __float2bfloat16(fv[e]);
            us[e] = *(unsigned short*)&bv;
        }
        *(ushort4*)&Af[row * 136 + c4] = up;
    }
    // zero pad cols 96..127: 512 ushort4, 2/thread
#pragma unroll
    for (int i = 0; i < 2; ++i) {
        int v = i * 256 + tid;
        int row = v >> 3;
        int c4 = 96 + (v & 7) * 4;
        ushort4 z; z.x = 0; z.y = 0; z.z = 0; z.w = 0;
        *(ushort4*)&Af[row * 136 + c4] = z;
    }

    const int lane = tid & 63;
    const int wid = tid >> 6;
    const int wr = (wid >> 1) * 32;       // M: 2 wave-rows of 32
    const int wc = (wid & 1) * 64;        // N: 2 wave-cols of 64
    const int srow = tid >> 3;
    const int schk = ((tid & 7) ^ (srow & 7)) * 8;
    const int sdst = tid * 16;
    const int fr = lane & 15;
    const int hi = lane >> 4;
    char* lW = (char*)Ws + sdst;

    f32x4 acc[3][2][4] = {};              // [gate][mi][ni], all static-indexed
#pragma unroll
    for (int g = 0; g < 3; ++g) {
        const bf16* gw = W + (size_t)(g * 1024 + jt * 128 + srow) * 128 + schk;
        for (int kt = 0; kt < 2; ++kt) {
            __syncthreads();              // Ws overwrite guard (also Af ready, 1st it)
#pragma unroll
            for (int m = 0; m < 4; ++m)
                llds16(gw + (size_t)(32 * m) * 128, lW + 32 * m * 128);
            gw += 64;
            __syncthreads();
#pragma unroll
            for (int kk = 0; kk < 2; ++kk) {
                bf16x8 af[2], wf[4];
                const int wchk = (((kk << 2) + hi) ^ (fr & 7)) * 8;
                const int achk = kt * 64 + ((kk << 2) + hi) * 8;
#pragma unroll
                for (int i = 0; i < 2; ++i)
                    af[i] = *(const bf16x8*)&Af[(wr + i * 16 + fr) * 136 + achk];
#pragma unroll
                for (int i = 0; i < 4; ++i)
                    wf[i] = *(const bf16x8*)&Ws[(wc + i * 16 + fr) * 64 + wchk];
#pragma unroll
                for (int mi = 0; mi < 2; ++mi)
#pragma unroll
                    for (int ni = 0; ni < 4; ++ni)
                        acc[g][mi][ni] = __builtin_amdgcn_mfma_f32_16x16x32_bf16(
                            af[mi], wf[ni], acc[g][mi][ni], 0, 0, 0);
            }
        }
    }

    // cell0 on register gates: elem (row = tm+wr+mi*16+fq+r, j = jt*128+wc+ni*16+fr)
    const int fq = hi * 4;
#pragma unroll
    for (int mi = 0; mi < 2; ++mi)
#pragma unroll
        for (int ni = 0; ni < 4; ++ni) {
            const int j = jt * 128 + wc + ni * 16 + fr;
            const float br = bias[j];
            const float bz = bias[1024 + j];
            const float bn = bias[2048 + j];
#pragma unroll
            for (int r = 0; r < 4; ++r) {
                const int row = tm + wr + mi * 16 + fq + r;
                const float ir = acc[0][mi][ni][r] + br;
                const float iz = acc[1][mi][ni][r] + bz;
                const float in_ = acc[2][mi][ni][r] + bn;
                size_t gbase = (size_t)row * H3 + j;
                const float hr = b2f(gh[gbase]);
                const float hz = b2f(gh[gbase + Hh]);
                const float hn = b2f(gh[gbase + 2 * Hh]);
                size_t ho = (size_t)row * Hh + j;
                const float hold = h[ho];
                float rr = 1.f / (1.f + __expf(-(ir + hr)));
                float zz = 1.f / (1.f + __expf(-(iz + hz)));
                float nn = tanhf(in_ + rr * hn);
                float v = (1.f - zz) * nn + zz * hold;
                h[ho] = v;
                hb[ho] = __float2bfloat16(v);
            }
        }
}

// 64x64-tile GEMM with split-K (grid.z = nsplit); fp32 or bf16 out. (setup only)
template <bool OUT_BF16>
__global__ void __launch_bounds__(256)
gemm64(const bf16* __restrict__ A, const bf16* __restrict__ W,
       const float* __restrict__ bias, void* __restrict__ Cout,
       int M, int Nreal, int Ktot, int Ks, int lda, int ldc)
{
    __shared__ bf16 As[64 * 32];
    __shared__ bf16 Ws[64 * 32];
    int bx, by, bz;
    swz_decomp(bx, by, bz);
    const int s = bz;
    const float* bs = (s == 0) ? bias : nullptr;
    const int tid = threadIdx.x;
    const int lane = tid & 63;
    const int wid = tid >> 6;
    const int wr = (wid >> 1) * 32;
    const int wc = (wid & 1) * 32;
    const int tm = by * 64;
    const int tn = bx * 64;
    const int srow = tid >> 2;
    const int skb = (tid & 3) * 8;
    const int k0 = s * Ks;

    f32x4 acc[2][2] = {};

    const bf16* ga = A + (size_t)(tm + srow) * lda + k0 + skb;
    const bf16* gw = W + (size_t)(tn + srow) * Ktot + k0 + skb;
    bf16* lA = &As[srow * 32 + skb];
    bf16* lW = &Ws[srow * 32 + skb];
    const int nk = Ks >> 5;

    for (int kt = 0; kt < nk; ++kt) {
        llds16(ga, lA);
        llds16(gw, lW);
        ga += 32; gw += 32;
        __syncthreads();
        const int fr = lane & 15;
        const int kg = (lane >> 4) * 8;
        bf16x8 af[2], wf[2];
#pragma unroll
        for (int i = 0; i < 2; ++i) {
            af[i] = *(const bf16x8*)&As[(wr + i * 16 + fr) * 32 + kg];
            wf[i] = *(const bf16x8*)&Ws[(wc + i * 16 + fr) * 32 + kg];
        }
#pragma unroll
        for (int mi = 0; mi < 2; ++mi)
#pragma unroll
            for (int ni = 0; ni < 2; ++ni)
                acc[mi][ni] = __builtin_amdgcn_mfma_f32_16x16x32_bf16(
                    af[mi], wf[ni], acc[mi][ni], 0, 0, 0);
        __syncthreads();
    }

    float* Cf = (float*)Cout + (size_t)s * M * ldc;
    const int fr = lane & 15;
    const int fq = (lane >> 4) * 4;
#pragma unroll
    for (int mi = 0; mi < 2; ++mi)
#pragma unroll
        for (int ni = 0; ni < 2; ++ni) {
            const int col = tn + wc + ni * 16 + fr;
            if (col < Nreal) {
                const float bv = bs ? bs[col] : 0.f;
#pragma unroll
                for (int r = 0; r < 4; ++r) {
                    const int row = tm + wr + mi * 16 + fq + r;
                    const float v = acc[mi][ni][r] + bv;
                    if constexpr (OUT_BF16)
                        ((bf16*)Cout)[(size_t)row * ldc + col] = __float2bfloat16(v);
                    else
                        Cf[(size_t)row * ldc + col] = v;
                }
            }
        }
}

__global__ void cvt_k(const float* __restrict__ s, bf16* __restrict__ d, int n) {
    int i = blockIdx.x * blockDim.x + threadIdx.x;
    if (i < n) d[i] = __float2bfloat16(s[i]);
}

// src [n][96] fp32 -> dst [n][128] bf16, pad cols zero
__global__ void cvtpad_k(const float* __restrict__ s, bf16* __restrict__ d, int n) {
    int o = blockIdx.x * blockDim.x + threadIdx.x;
    if (o >= n * 128) return;
    int r = o >> 7, c = o & 127;
    d[o] = __float2bfloat16(c < Ii ? s[(size_t)r * Ii + c] : 0.f);
}

// x[B][T][96] fp32 -> xbT[T][B][128] bf16 (pad cols zero)
__global__ void tpose_k(const float* __restrict__ x, bf16* __restrict__ d) {
    int o = blockIdx.x * blockDim.x + threadIdx.x;
    if (o >= Tt * Bsz * 128) return;
    int i = o & 127;
    int b = (o >> 7) & (Bsz - 1);
    int t = o >> 17;
    d[o] = __float2bfloat16(i < Ii ? x[((size_t)b * Tt + t) * Ii + i] : 0.f);
}

// fcin_w [H][96] fp32 -> fcinT [128(pad)][H] bf16 (rows >= Ii zero)
__global__ void tposeFcin_k(const float* __restrict__ w, bf16* __restrict__ d) {
    int o = blockIdx.x * blockDim.x + threadIdx.x;
    if (o >= 128 * Hh) return;
    int r = o >> 10;
    int c = o & (Hh - 1);
    float v = (r < Ii) ? w[(size_t)c * Ii + r] : 0.f;
    d[o] = __float2bfloat16(v);
}

// bcomb[n] = dot(dWih0[n,:], fcin_b) + dbih0[n] ; one block per n
__global__ void __launch_bounds__(256)
bcomb_k(const float* __restrict__ W, const float* __restrict__ v,
        const float* __restrict__ b2, float* __restrict__ o) {
    __shared__ float red[256];
    int n = blockIdx.x;
    float s = 0.f;
    for (int k = threadIdx.x; k < Hh; k += 256)
        s += W[(size_t)n * Hh + k] * v[k];
    red[threadIdx.x] = s;
    __syncthreads();
    for (int w = 128; w > 0; w >>= 1) {
        if (threadIdx.x < w) red[threadIdx.x] += red[threadIdx.x + w];
        __syncthreads();
    }
    if (threadIdx.x == 0) o[n] = red[0] + b2[n];
}

__global__ void prefix_k(const float* __restrict__ x, float* __restrict__ out) {
    int idx = blockIdx.x * blockDim.x + threadIdx.x;
    if (idx >= Bsz * Pp * Ii) return;
    int b = idx / (Pp * Ii);
    int r = idx % (Pp * Ii);
    out[(size_t)b * Tt * Ii + r] = x[(size_t)b * Tt * Ii + r];
}

__global__ void finit_k(const float* __restrict__ x, float* __restrict__ fr,
                        bf16* __restrict__ frb) {
    int idx = blockIdx.x * blockDim.x + threadIdx.x;
    if (idx >= Bsz * Ii) return;
    int b = idx / Ii;
    int i = idx % Ii;
    float v = x[(size_t)b * Tt * Ii + (Pp - 1) * Ii + i];
    fr[idx] = v;
    frb[(size_t)b * 128 + i] = __float2bfloat16(v);
}

// GRU cell body; gates bf16, math fp32, h state fp32
#define CELL_BODY(IDX, GI, GH, H, HB)                                        \
    {                                                                        \
        int b_ = (IDX) >> 8;                                                 \
        int j_ = ((IDX) & 255) << 2;                                         \
        size_t base_ = (size_t)b_ * H3 + j_;                                 \
        f32x4 ir = ldb4((GI) + base_);                                       \
        f32x4 iz = ldb4((GI) + base_ + Hh);                                  \
        f32x4 in = ldb4((GI) + base_ + 2 * Hh);                              \
        f32x4 hr = ldb4((GH) + base_);                                       \
        f32x4 hz = ldb4((GH) + base_ + Hh);                                  \
        f32x4 hn = ldb4((GH) + base_ + 2 * Hh);                              \
        size_t hoff_ = (size_t)b_ * Hh + j_;                                 \
        f32x4 hold = *(const f32x4*)((H) + hoff_);                           \
        f32x4 hv;                                                            \
        ushort4 up;                                                          \
        unsigned short* us = &up.x;                                          \
        _Pragma("unroll")                                                    \
        for (int e = 0; e < 4; ++e) {                                        \
            float r = 1.f / (1.f + __expf(-(ir[e] + hr[e])));                \
            float z = 1.f / (1.f + __expf(-(iz[e] + hz[e])));                \
            float n = tanhf(in[e] + r * hn[e]);                              \
            float v = (1.f - z) * n + z * hold[e];                           \
            hv[e] = v;                                                       \
            bf16 bv = __float2bfloat16(v);                                   \
            us[e] = *(unsigned short*)&bv;                                   \
        }                                                                    \
        *(f32x4*)((H) + hoff_) = hv;                                         \
        *(ushort4*)((unsigned short*)(HB) + hoff_) = up;                     \
    }

__global__ void __launch_bounds__(256)
gru_cell_k(const bf16* __restrict__ gi, const bf16* __restrict__ gh,
           float* __restrict__ h, bf16* __restrict__ hb) {
    int idx = blockIdx.x * 256 + threadIdx.x;
    CELL_BODY(idx, gi, gh, h, hb);
}

// two independent cells in one launch (grid = 2048)
__global__ void __launch_bounds__(256)
gru_cell2_k(const bf16* __restrict__ giA, const bf16* __restrict__ ghA,
            float* __restrict__ hA, bf16* __restrict__ hbA,
            const bf16* __restrict__ giB, const bf16* __restrict__ ghB,
            float* __restrict__ hB, bf16* __restrict__ hbB) {
    int bid = blockIdx.x;
    const bf16* gi = giA;
    const bf16* gh = ghA;
    float* h = hA;
    bf16* hb = hbA;
    if (bid >= 1024) {
        gi = giB; gh = ghB; h = hB; hb = hbB;
        bid -= 1024;
    }
    int idx = bid * 256 + threadIdx.x;
    CELL_BODY(idx, gi, gh, h, hb);
}

extern "C" void kernel_launch(void* const* d_in, const int* in_sizes, int n_in,
                              void* d_out, int out_size, void* d_ws, size_t ws_size,
                              hipStream_t stream) {
    const float* x      = (const float*)d_in[0];
    const float* eWih0  = (const float*)d_in[1];
    const float* eWhh0  = (const float*)d_in[2];
    const float* ebih0  = (const float*)d_in[3];
    const float* ebhh0  = (const float*)d_in[4];
    const float* eWih1  = (const float*)d_in[5];
    const float* eWhh1  = (const float*)d_in[6];
    const float* ebih1  = (const float*)d_in[7];
    const float* ebhh1  = (const float*)d_in[8];
    const float* dWih0  = (const float*)d_in[9];
    const float* dWhh0  = (const float*)d_in[10];
    const float* dbih0  = (const float*)d_in[11];
    const float* dbhh0  = (const float*)d_in[12];
    const float* dWih1  = (const float*)d_in[13];
    const float* dWhh1  = (const float*)d_in[14];
    const float* dbih1  = (const float*)d_in[15];
    const float* dbhh1  = (const float*)d_in[16];
    const float* fcin_w = (const float*)d_in[17];
    const float* fcin_b = (const float*)d_in[18];
    const float* fcout_w= (const float*)d_in[19];
    const float* fcout_b= (const float*)d_in[20];
    float* out = (float*)d_out;

    char* base = (char*)d_ws;
    size_t off = 0;
    auto alloc = [&](size_t bytes) -> void* {
        void* r = base + off;
        off += (bytes + 255) & ~(size_t)255;
        return r;
    };
    bf16* wWih0e = (bf16*)alloc((size_t)H3 * 128 * 2);     // K-padded 96->128
    bf16* wWhh0e = (bf16*)alloc((size_t)H3 * Hh * 2);
    bf16* wWih1e = (bf16*)alloc((size_t)H3 * Hh * 2);
    bf16* wWhh1e = (bf16*)alloc((size_t)H3 * Hh * 2);
    bf16* wWhh0d = (bf16*)alloc((size_t)H3 * Hh * 2);
    bf16* wWih1d = (bf16*)alloc((size_t)H3 * Hh * 2);
    bf16* wWhh1d = (bf16*)alloc((size_t)H3 * Hh * 2);
    bf16* wWih0d = (bf16*)alloc((size_t)H3 * Hh * 2);
    bf16* fcinT  = (bf16*)alloc((size_t)128 * Hh * 2);     // fcin_w^T padded
    bf16* wWcomb = (bf16*)alloc((size_t)H3 * 128 * 2);     // dWih0 @ fcin_w, K-pad
    float* bcomb = (float*)alloc((size_t)H3 * 4);
    bf16* wfcout = (bf16*)alloc((size_t)128 * Hh * 2);     // padded 96->128 rows
    float* zbias = (float*)alloc((size_t)128 * 4);
    bf16* xbT    = (bf16*)alloc((size_t)Tt * Bsz * 128 * 2);
    bf16* gi1_p  = (bf16*)alloc((size_t)Bsz * H3 * 2);
    bf16* gh1_p  = (bf16*)alloc((size_t)Bsz * H3 * 2);
    bf16* gh0_p  = (bf16*)alloc((size_t)Bsz * H3 * 2);
    bf16* gi0_p  = (bf16*)alloc((size_t)Bsz * H3 * 2);
    float* h0    = (float*)alloc((size_t)Bsz * Hh * 4);
    float* h1A   = (float*)alloc((size_t)Bsz * Hh * 4);
    float* h1B   = (float*)alloc((size_t)Bsz * Hh * 4);    // decoder ping-pong
    bf16* h0b    = (bf16*)alloc((size_t)Bsz * Hh * 2);
    bf16* h1b    = (bf16*)alloc((size_t)Bsz * Hh * 2);
    float* gfc   = (float*)alloc((size_t)8 * Bsz * Ii * 4);
    float* fbuf0 = (float*)alloc((size_t)Bsz * Ii * 4);
    float* fbuf1 = (float*)alloc((size_t)Bsz * Ii * 4);
    bf16* frameb = (bf16*)alloc((size_t)Bsz * 128 * 2);    // row stride 128
    unsigned long long* tab = (unsigned long long*)alloc(8 * 8 * 8);
    if (off > ws_size) return;

    auto cvt = [&](const float* s, bf16* d, int n) {
        cvt_k<<<dim3((n + 255) / 256), dim3(256), 0, stream>>>(s, d, n);
    };
    cvtpad_k<<<dim3((H3 * 128 + 255) / 256), dim3(256), 0, stream>>>(eWih0, wWih0e, H3);
    cvt(eWhh0, wWhh0e, H3 * Hh);
    cvt(eWih1, wWih1e, H3 * Hh);
    cvt(eWhh1, wWhh1e, H3 * Hh);
    cvt(dWih0, wWih0d, H3 * Hh);
    cvt(dWhh0, wWhh0d, H3 * Hh);
    cvt(dWih1, wWih1d, H3 * Hh);
    cvt(dWhh1, wWhh1d, H3 * Hh);
    (void)hipMemsetAsync(wfcout, 0, (size_t)128 * Hh * 2, stream);
    (void)hipMemsetAsync(wWcomb, 0, (size_t)H3 * 128 * 2, stream);
    (void)hipMemsetAsync(zbias, 0, (size_t)128 * 4, stream);
    (void)hipMemsetAsync(frameb, 0, (size_t)Bsz * 128 * 2, stream);
    cvt(fcout_w, wfcout, Ii * Hh);
    // fc_in composition: Wcomb = dWih0 @ fcin_w (ldc=128) ; bcomb = dWih0@fcin_b + dbih0
    tposeFcin_k<<<dim3((128 * Hh + 255) / 256), dim3(256), 0, stream>>>(fcin_w, fcinT);
    gemm64<true><<<dim3(2, 48, 1), dim3(256), 0, stream>>>(
        wWih0d, fcinT, zbias, (void*)wWcomb, H3, Ii, Hh, Hh, Hh, 128);
    bcomb_k<<<dim3(H3), dim3(256), 0, stream>>>(dWih0, fcin_b, dbih0, bcomb);

    tpose_k<<<dim3((Tt * Bsz * 128 + 255) / 256), dim3(256), 0, stream>>>(x, xbT);
    prefix_k<<<dim3((Bsz * Pp * Ii + 255) / 256), dim3(256), 0, stream>>>(x, out);
    finit_k<<<dim3((Bsz * Ii + 255) / 256), dim3(256), 0, stream>>>(x, fbuf0, frameb);
    (void)hipMemsetAsync(h0, 0, (size_t)Bsz * Hh * 4, stream);
    (void)hipMemsetAsync(h1A, 0, (size_t)Bsz * Hh * 4, stream);
    (void)hipMemsetAsync(h0b, 0, (size_t)Bsz * Hh * 2, stream);
    (void)hipMemsetAsync(h1b, 0, (size_t)Bsz * Hh * 2, stream);

    // descriptor table (8 slots):
    // 0: enc gi1   1: enc gh1   2: enc gh0   3: enc gi0 (A=extra xbT+t, K=128)
    // 4: dec gi1   5: dec gh1   6: dec gh0   7: dec gi0 (frameb @ Wcomb, K=128)
    wdesc_k<<<1, 64, 0, stream>>>(tab + 0 * 8, h0b, wWih1e, ebih1, gi1_p, Hh, Hh);
    wdesc_k<<<1, 64, 0, stream>>>(tab + 1 * 8, h1b, wWhh1e, ebhh1, gh1_p, Hh, Hh);
    wdesc_k<<<1, 64, 0, stream>>>(tab + 2 * 8, h0b, wWhh0e, ebhh0, gh0_p, Hh, Hh);
    wdesc_k<<<1, 64, 0, stream>>>(tab + 3 * 8, nullptr, wWih0e, ebih0, gi0_p, 128, 128);
    wdesc_k<<<1, 64, 0, stream>>>(tab + 4 * 8, h0b, wWih1d, dbih1, gi1_p, Hh, Hh);
    wdesc_k<<<1, 64, 0, stream>>>(tab + 5 * 8, h1b, wWhh1d, dbhh1, gh1_p, Hh, Hh);
    wdesc_k<<<1, 64, 0, stream>>>(tab + 6 * 8, h0b, wWhh0d, dbhh0, gh0_p, Hh, Hh);
    wdesc_k<<<1, 64, 0, stream>>>(tab + 7 * 8, frameb, wWcomb, bcomb, gi0_p, 128, 128);

    // ---- encoder ---- (unchanged from R9; h1 lives in h1A)
    gemm_tab<<<dim3(384), dim3(256), 0, stream>>>(tab, 2, 2, xbT);
    gru_cell_k<<<dim3(1024), dim3(256), 0, stream>>>(gi0_p, gh0_p, h0, h0b);
    for (int i = 0; i < Pp; ++i) {
        if (i < Pp - 1) {
            gemm_tab<<<dim3(768), dim3(256), 0, stream>>>(
                tab, 0, 4, xbT + (size_t)(i + 1) * Bsz * 128);
            gru_cell2_k<<<dim3(2048), dim3(256), 0, stream>>>(
                gi1_p, gh1_p, h1A, h1b, gi0_p, gh0_p, h0, h0b);
        } else {
            gemm_tab<<<dim3(384), dim3(256), 0, stream>>>(tab, 0, 2, xbT);
            gru_cell_k<<<dim3(1024), dim3(256), 0, stream>>>(gi1_p, gh1_p, h1A, h1b);
        }
    }

    // ---- decoder ----
    // init: gh0 (h_enc0) + gi0 (frame_0 via Wcomb @ frameb) -> hd0(step 0)
    gemm_tab<<<dim3(384), dim3(256), 0, stream>>>(tab, 6, 2, xbT);
    gru_cell_k<<<dim3(1024), dim3(256), 0, stream>>>(gi0_p, gh0_p, h0, h0b);
    for (int t = 0; t < Tt - Pp; ++t) {
        const bool last = (t == Tt - Pp - 1);
        if (!last)
            gemm_tab<<<dim3(576), dim3(256), 0, stream>>>(tab, 4, 3, xbT);
        else
            gemm_tab<<<dim3(384), dim3(256), 0, stream>>>(tab, 4, 2, xbT);
        // fused cell1 + fc_out (h1 ping-pong: t=0 reads encoder's h1A)
        cellfc_k<<<dim3(256), dim3(256), 0, stream>>>(
            gi1_p, gh1_p, (t & 1) ? h1B : h1A, (t & 1) ? h1A : h1B, h1b,
            wfcout, fcout_b, gfc);
        // fused frame update + gi0 GEMM + cell0 (h0 in-place; last step's
        // h0/h0b writes consume stale gh0 but are never read -> harmless)
        megafuse_k<<<dim3(128), dim3(256), 0, stream>>>(
            gfc, (t & 1) ? fbuf1 : fbuf0, (t & 1) ? fbuf0 : fbuf1,
            out + (size_t)(Pp + t) * Ii, wWcomb, bcomb, gh0_p, h0, h0b);
    }
}

// Round 11
// 4929.878 us; speedup vs baseline: 1.0993x; 1.0993x over previous
//
#include <hip/hip_runtime.h>
#include <hip/hip_bf16.h>
#include <stdint.h>

#define Bsz 1024
#define Tt  100
#define Pp  50
#define Ii  96
#define Hh  1024
#define H3  3072

typedef __bf16 bf16x8 __attribute__((ext_vector_type(8)));
typedef float f32x4 __attribute__((ext_vector_type(4)));
typedef __hip_bfloat16 bf16;

__device__ __forceinline__ void llds16(const void* g, void* l) {
    __builtin_amdgcn_global_load_lds(
        (const __attribute__((address_space(1))) void*)g,
        (__attribute__((address_space(3))) void*)l,
        16, 0, 0);
}

// bf16x4 (as ushort4) -> f32x4, exact
__device__ __forceinline__ f32x4 ldb4(const bf16* p) {
    ushort4 u = *(const ushort4*)p;
    union { unsigned int i; float f; } c;
    f32x4 r;
    c.i = (unsigned int)u.x << 16; r[0] = c.f;
    c.i = (unsigned int)u.y << 16; r[1] = c.f;
    c.i = (unsigned int)u.z << 16; r[2] = c.f;
    c.i = (unsigned int)u.w << 16; r[3] = c.f;
    return r;
}

__device__ __forceinline__ void swz_decomp(int& bx, int& by, int& bz) {
    int gx = gridDim.x, gy = gridDim.y, gz = gridDim.z;
    int flat = blockIdx.x + gx * (blockIdx.y + gy * blockIdx.z);
    int tot = gx * gy * gz;
    if (!(tot & 7)) {
        int q = tot >> 3;
        flat = (flat & 7) * q + (flat >> 3);
    }
    bx = flat % gx;
    int rest = flat / gx;
    by = rest % gy;
    bz = rest / gy;
}

// descriptor slot writer: slot = {A, W, bias, C, K, lda, 0, 0}
__global__ void wdesc_k(unsigned long long* slot, const void* A, const void* W,
                        const void* b, void* C, int K, int lda) {
    if (threadIdx.x == 0) {
        slot[0] = (unsigned long long)A;
        slot[1] = (unsigned long long)W;
        slot[2] = (unsigned long long)b;
        slot[3] = (unsigned long long)C;
        slot[4] = (unsigned long long)K;
        slot[5] = (unsigned long long)lda;
    }
}

// Batched GEMM from descriptor table, BK=64, XOR-swizzled LDS.
// Descriptor g (of ndesc) owns 192 blocks (24 N-tiles x 8 M-tiles):
// C[1024x3072](bf16) = A[1024xK(lda)] @ W[3072xK]^T + bias.  K % 64 == 0.
// Slot with A==0 uses extraA. grid = ndesc*192 (1-D).
__global__ void __launch_bounds__(256)
gemm_tab(const unsigned long long* __restrict__ tab, int base, int ndesc,
         const bf16* __restrict__ extraA)
{
    __shared__ bf16 As[128 * 64];
    __shared__ bf16 Ws[128 * 64];
    int flat = blockIdx.x;
    const int tot = ndesc * 192;
    if (!(tot & 7)) {
        int q = tot >> 3;
        flat = (flat & 7) * q + (flat >> 3);
    }
    const int g = flat / 192;
    const int local = flat - g * 192;
    const unsigned long long* dp = tab + (size_t)(base + g) * 8;
    const bf16* A = (const bf16*)dp[0];
    const bf16* W = (const bf16*)dp[1];
    const float* bias = (const float*)dp[2];
    bf16* C = (bf16*)dp[3];
    const int K = (int)dp[4];
    const int lda = (int)dp[5];
    if (!A) A = extraA;

    const int tn = (local % 24) * 128;
    const int tm = (local / 24) * 128;

    const int tid = threadIdx.x;
    const int lane = tid & 63;
    const int wid = tid >> 6;              // 4 waves: 2x2 of 64x64
    const int wr = (wid >> 1) * 64;
    const int wc = (wid & 1) * 64;
    const int srow = tid >> 3;             // 0..31 (8 threads x 16B per 128B row)
    const int schk = ((tid & 7) ^ (srow & 7)) * 8;  // swizzled global chunk (elems)
    const int sdst = tid * 16;             // linear LDS byte offset (lane-linear)
    const int fr = lane & 15;
    const int hi = lane >> 4;

    f32x4 acc[4][4] = {};

    const bf16* ga = A + (size_t)(tm + srow) * lda + schk;
    const bf16* gw = W + (size_t)(tn + srow) * K + schk;
    char* lA = (char*)As + sdst;
    char* lW = (char*)Ws + sdst;
    const int nk = K >> 6;

    for (int kt = 0; kt < nk; ++kt) {
#pragma unroll
        for (int m = 0; m < 4; ++m) {
            llds16(ga + (size_t)(32 * m) * lda, lA + 32 * m * 128);
            llds16(gw + (size_t)(32 * m) * K,  lW + 32 * m * 128);
        }
        ga += 64; gw += 64;
        __syncthreads();

#pragma unroll
        for (int kk = 0; kk < 2; ++kk) {
            bf16x8 af[4], wf[4];
            const int chk = (((kk << 2) + hi) ^ (fr & 7)) * 8;
#pragma unroll
            for (int i = 0; i < 4; ++i) {
                af[i] = *(const bf16x8*)&As[(wr + i * 16 + fr) * 64 + chk];
                wf[i] = *(const bf16x8*)&Ws[(wc + i * 16 + fr) * 64 + chk];
            }
#pragma unroll
            for (int mi = 0; mi < 4; ++mi)
#pragma unroll
                for (int ni = 0; ni < 4; ++ni)
                    acc[mi][ni] = __builtin_amdgcn_mfma_f32_16x16x32_bf16(
                        af[mi], wf[ni], acc[mi][ni], 0, 0, 0);
        }
        __syncthreads();
    }

    const int fq = hi * 4;
#pragma unroll
    for (int mi = 0; mi < 4; ++mi)
#pragma unroll
        for (int ni = 0; ni < 4; ++ni) {
            const int col = tn + wc + ni * 16 + fr;
            const float bv = bias[col];
#pragma unroll
            for (int r = 0; r < 4; ++r) {
                const int row = tm + wr + mi * 16 + fq + r;
                C[(size_t)row * H3 + col] = __float2bfloat16(acc[mi][ni][r] + bv);
            }
        }
}

// Fused: sum 8 fc_out partials + frame -> frame_new (fp32 pong + out rows by
// tn==0 blocks) -> bf16 LDS A-tile -> K=128 GEMM vs Wcomb -> gi0(bf16) + bcomb.
// grid = 384 (24 tn x 16 tm, 64-row M tiles).  Coalesced phase A.
__global__ void __launch_bounds__(256)
fuse_fg_k(const float* __restrict__ gp,     // [8][Bsz][Ii] partials (bias in p0)
          const float* __restrict__ fin,    // frame in  [Bsz][Ii]
          float* __restrict__ fout,         // frame out [Bsz][Ii]
          float* __restrict__ out_t,        // out + (Pp+t)*Ii, row stride Tt*Ii
          const bf16* __restrict__ W,       // Wcomb [H3][128]
          const float* __restrict__ bias,   // bcomb [H3]
          bf16* __restrict__ C)             // gi0_p [Bsz][H3] bf16
{
    __shared__ bf16 Af[64 * 136];           // A-tile, +8 pad -> conflict-free b128
    __shared__ bf16 Ws[128 * 64];
    int flat = blockIdx.x;
    { int q = 384 >> 3; flat = (flat & 7) * q + (flat >> 3); }
    const int tn = (flat % 24) * 128;
    const int tm = (flat / 24) * 64;
    const int tid = threadIdx.x;

    // phase A: frame tile (64 rows x 96 cols = 1536 f32x4), lane-consecutive
#pragma unroll
    for (int i = 0; i < 6; ++i) {
        int v = i * 256 + tid;              // consecutive lanes -> consecutive f32x4
        int row = v / 24;
        int c4 = (v % 24) * 4;
        size_t go = (size_t)(tm + row) * Ii + c4;
        f32x4 s = {};
#pragma unroll
        for (int p = 0; p < 8; ++p)
            s += *(const f32x4*)(gp + (size_t)p * (Bsz * Ii) + go);
        f32x4 fv = *(const f32x4*)(fin + go) + s;
        if (tn == 0) {
            *(f32x4*)(fout + go) = fv;
            *(f32x4*)(out_t + (size_t)(tm + row) * (Tt * Ii) + c4) = fv;
        }
        ushort4 up;
        unsigned short* us = &up.x;
#pragma unroll
        for (int e = 0; e < 4; ++e) {
            bf16 bv = __float2bfloat16(fv[e]);
            us[e] = *(unsigned short*)&bv;
        }
        *(ushort4*)&Af[row * 136 + c4] = up;
    }
    // zero pad cols 96..127 (avoid NaN garbage feeding MFMA): 512 ushort4
#pragma unroll
    for (int i = 0; i < 2; ++i) {
        int v = i * 256 + tid;
        int row = v >> 3;
        int c4 = 96 + (v & 7) * 4;
        ushort4 z; z.x = 0; z.y = 0; z.z = 0; z.w = 0;
        *(ushort4*)&Af[row * 136 + c4] = z;
    }

    const int lane = tid & 63;
    const int wid = tid >> 6;
    const int wr = (wid >> 1) * 32;        // M=64: 2 wave-rows of 32
    const int wc = (wid & 1) * 64;         // N=128: 2 wave-cols of 64
    const int srow = tid >> 3;
    const int schk = ((tid & 7) ^ (srow & 7)) * 8;
    const int sdst = tid * 16;
    const int fr = lane & 15;
    const int hi = lane >> 4;

    f32x4 acc[2][4] = {};
    const bf16* gw = W + (size_t)(tn + srow) * 128 + schk;
    char* lW = (char*)Ws + sdst;

    for (int kt = 0; kt < 2; ++kt) {
#pragma unroll
        for (int m = 0; m < 4; ++m)
            llds16(gw + (size_t)(32 * m) * 128, lW + 32 * m * 128);
        gw += 64;
        __syncthreads();
#pragma unroll
        for (int kk = 0; kk < 2; ++kk) {
            bf16x8 af[2], wf[4];
            const int wchk = (((kk << 2) + hi) ^ (fr & 7)) * 8;
            const int achk = kt * 64 + ((kk << 2) + hi) * 8;
#pragma unroll
            for (int i = 0; i < 2; ++i)
                af[i] = *(const bf16x8*)&Af[(wr + i * 16 + fr) * 136 + achk];
#pragma unroll
            for (int i = 0; i < 4; ++i)
                wf[i] = *(const bf16x8*)&Ws[(wc + i * 16 + fr) * 64 + wchk];
#pragma unroll
            for (int mi = 0; mi < 2; ++mi)
#pragma unroll
                for (int ni = 0; ni < 4; ++ni)
                    acc[mi][ni] = __builtin_amdgcn_mfma_f32_16x16x32_bf16(
                        af[mi], wf[ni], acc[mi][ni], 0, 0, 0);
        }
        __syncthreads();
    }

    const int fq = hi * 4;
#pragma unroll
    for (int mi = 0; mi < 2; ++mi)
#pragma unroll
        for (int ni = 0; ni < 4; ++ni) {
            const int col = tn + wc + ni * 16 + fr;
            const float bv = bias[col];
#pragma unroll
            for (int r = 0; r < 4; ++r) {
                const int row = tm + wr + mi * 16 + fq + r;
                C[(size_t)row * H3 + col] = __float2bfloat16(acc[mi][ni][r] + bv);
            }
        }
}

// 64x64-tile GEMM with split-K (grid.z = nsplit); fp32 or bf16 out. (BK=32)
template <bool OUT_BF16>
__global__ void __launch_bounds__(256)
gemm64(const bf16* __restrict__ A, const bf16* __restrict__ W,
       const float* __restrict__ bias, void* __restrict__ Cout,
       int M, int Nreal, int Ktot, int Ks, int lda, int ldc)
{
    __shared__ bf16 As[64 * 32];
    __shared__ bf16 Ws[64 * 32];
    int bx, by, bz;
    swz_decomp(bx, by, bz);
    const int s = bz;
    const float* bs = (s == 0) ? bias : nullptr;
    const int tid = threadIdx.x;
    const int lane = tid & 63;
    const int wid = tid >> 6;
    const int wr = (wid >> 1) * 32;
    const int wc = (wid & 1) * 32;
    const int tm = by * 64;
    const int tn = bx * 64;
    const int srow = tid >> 2;
    const int skb = (tid & 3) * 8;
    const int k0 = s * Ks;

    f32x4 acc[2][2] = {};

    const bf16* ga = A + (size_t)(tm + srow) * lda + k0 + skb;
    const bf16* gw = W + (size_t)(tn + srow) * Ktot + k0 + skb;
    bf16* lA = &As[srow * 32 + skb];
    bf16* lW = &Ws[srow * 32 + skb];
    const int nk = Ks >> 5;

    for (int kt = 0; kt < nk; ++kt) {
        llds16(ga, lA);
        llds16(gw, lW);
        ga += 32; gw += 32;
        __syncthreads();
        const int fr = lane & 15;
        const int kg = (lane >> 4) * 8;
        bf16x8 af[2], wf[2];
#pragma unroll
        for (int i = 0; i < 2; ++i) {
            af[i] = *(const bf16x8*)&As[(wr + i * 16 + fr) * 32 + kg];
            wf[i] = *(const bf16x8*)&Ws[(wc + i * 16 + fr) * 32 + kg];
        }
#pragma unroll
        for (int mi = 0; mi < 2; ++mi)
#pragma unroll
            for (int ni = 0; ni < 2; ++ni)
                acc[mi][ni] = __builtin_amdgcn_mfma_f32_16x16x32_bf16(
                    af[mi], wf[ni], acc[mi][ni], 0, 0, 0);
        __syncthreads();
    }

    float* Cf = (float*)Cout + (size_t)s * M * ldc;
    const int fr = lane & 15;
    const int fq = (lane >> 4) * 4;
#pragma unroll
    for (int mi = 0; mi < 2; ++mi)
#pragma unroll
        for (int ni = 0; ni < 2; ++ni) {
            const int col = tn + wc + ni * 16 + fr;
            if (col < Nreal) {
                const float bv = bs ? bs[col] : 0.f;
#pragma unroll
                for (int r = 0; r < 4; ++r) {
                    const int row = tm + wr + mi * 16 + fq + r;
                    const float v = acc[mi][ni][r] + bv;
                    if constexpr (OUT_BF16)
                        ((bf16*)Cout)[(size_t)row * ldc + col] = __float2bfloat16(v);
                    else
                        Cf[(size_t)row * ldc + col] = v;
                }
            }
        }
}

__global__ void cvt_k(const float* __restrict__ s, bf16* __restrict__ d, int n) {
    int i = blockIdx.x * blockDim.x + threadIdx.x;
    if (i < n) d[i] = __float2bfloat16(s[i]);
}

// src [n][96] fp32 -> dst [n][128] bf16, pad cols zero
__global__ void cvtpad_k(const float* __restrict__ s, bf16* __restrict__ d, int n) {
    int o = blockIdx.x * blockDim.x + threadIdx.x;
    if (o >= n * 128) return;
    int r = o >> 7, c = o & 127;
    d[o] = __float2bfloat16(c < Ii ? s[(size_t)r * Ii + c] : 0.f);
}

// x[B][T][96] fp32 -> xbT[T][B][128] bf16 (pad cols zero)
__global__ void tpose_k(const float* __restrict__ x, bf16* __restrict__ d) {
    int o = blockIdx.x * blockDim.x + threadIdx.x;
    if (o >= Tt * Bsz * 128) return;
    int i = o & 127;
    int b = (o >> 7) & (Bsz - 1);
    int t = o >> 17;
    d[o] = __float2bfloat16(i < Ii ? x[((size_t)b * Tt + t) * Ii + i] : 0.f);
}

// fcin_w [H][96] fp32 -> fcinT [128(pad)][H] bf16 (rows >= Ii zero)
__global__ void tposeFcin_k(const float* __restrict__ w, bf16* __restrict__ d) {
    int o = blockIdx.x * blockDim.x + threadIdx.x;
    if (o >= 128 * Hh) return;
    int r = o >> 10;
    int c = o & (Hh - 1);
    float v = (r < Ii) ? w[(size_t)c * Ii + r] : 0.f;
    d[o] = __float2bfloat16(v);
}

// bcomb[n] = dot(dWih0[n,:], fcin_b) + dbih0[n] ; one block per n
__global__ void __launch_bounds__(256)
bcomb_k(const float* __restrict__ W, const float* __restrict__ v,
        const float* __restrict__ b2, float* __restrict__ o) {
    __shared__ float red[256];
    int n = blockIdx.x;
    float s = 0.f;
    for (int k = threadIdx.x; k < Hh; k += 256)
        s += W[(size_t)n * Hh + k] * v[k];
    red[threadIdx.x] = s;
    __syncthreads();
    for (int w = 128; w > 0; w >>= 1) {
        if (threadIdx.x < w) red[threadIdx.x] += red[threadIdx.x + w];
        __syncthreads();
    }
    if (threadIdx.x == 0) o[n] = red[0] + b2[n];
}

__global__ void prefix_k(const float* __restrict__ x, float* __restrict__ out) {
    int idx = blockIdx.x * blockDim.x + threadIdx.x;
    if (idx >= Bsz * Pp * Ii) return;
    int b = idx / (Pp * Ii);
    int r = idx % (Pp * Ii);
    out[(size_t)b * Tt * Ii + r] = x[(size_t)b * Tt * Ii + r];
}

__global__ void finit_k(const float* __restrict__ x, float* __restrict__ fr,
                        bf16* __restrict__ frb) {
    int idx = blockIdx.x * blockDim.x + threadIdx.x;
    if (idx >= Bsz * Ii) return;
    int b = idx / Ii;
    int i = idx % Ii;
    float v = x[(size_t)b * Tt * Ii + (Pp - 1) * Ii + i];
    fr[idx] = v;
    frb[(size_t)b * 128 + i] = __float2bfloat16(v);
}

// GRU cell body; gates bf16, math fp32, h state fp32
#define CELL_BODY(IDX, GI, GH, H, HB)                                        \
    {                                                                        \
        int b_ = (IDX) >> 8;                                                 \
        int j_ = ((IDX) & 255) << 2;                                         \
        size_t base_ = (size_t)b_ * H3 + j_;                                 \
        f32x4 ir = ldb4((GI) + base_);                                       \
        f32x4 iz = ldb4((GI) + base_ + Hh);                                  \
        f32x4 in = ldb4((GI) + base_ + 2 * Hh);                              \
        f32x4 hr = ldb4((GH) + base_);                                       \
        f32x4 hz = ldb4((GH) + base_ + Hh);                                  \
        f32x4 hn = ldb4((GH) + base_ + 2 * Hh);                              \
        size_t hoff_ = (size_t)b_ * Hh + j_;                                 \
        f32x4 hold = *(const f32x4*)((H) + hoff_);                           \
        f32x4 hv;                                                            \
        ushort4 up;                                                          \
        unsigned short* us = &up.x;                                          \
        _Pragma("unroll")                                                    \
        for (int e = 0; e < 4; ++e) {                                        \
            float r = 1.f / (1.f + __expf(-(ir[e] + hr[e])));                \
            float z = 1.f / (1.f + __expf(-(iz[e] + hz[e])));                \
            float n = tanhf(in[e] + r * hn[e]);                              \
            float v = (1.f - z) * n + z * hold[e];                           \
            hv[e] = v;                                                       \
            bf16 bv = __float2bfloat16(v);                                   \
            us[e] = *(unsigned short*)&bv;                                   \
        }                                                                    \
        *(f32x4*)((H) + hoff_) = hv;                                         \
        *(ushort4*)((unsigned short*)(HB) + hoff_) = up;                     \
    }

__global__ void __launch_bounds__(256)
gru_cell_k(const bf16* __restrict__ gi, const bf16* __restrict__ gh,
           float* __restrict__ h, bf16* __restrict__ hb) {
    int idx = blockIdx.x * 256 + threadIdx.x;
    CELL_BODY(idx, gi, gh, h, hb);
}

// two independent cells in one launch (grid = 2048)
__global__ void __launch_bounds__(256)
gru_cell2_k(const bf16* __restrict__ giA, const bf16* __restrict__ ghA,
            float* __restrict__ hA, bf16* __restrict__ hbA,
            const bf16* __restrict__ giB, const bf16* __restrict__ ghB,
            float* __restrict__ hB, bf16* __restrict__ hbB) {
    int bid = blockIdx.x;
    const bf16* gi = giA;
    const bf16* gh = ghA;
    float* h = hA;
    bf16* hb = hbA;
    if (bid >= 1024) {
        gi = giB; gh = ghB; h = hB; hb = hbB;
        bid -= 1024;
    }
    int idx = bid * 256 + threadIdx.x;
    CELL_BODY(idx, gi, gh, h, hb);
}

extern "C" void kernel_launch(void* const* d_in, const int* in_sizes, int n_in,
                              void* d_out, int out_size, void* d_ws, size_t ws_size,
                              hipStream_t stream) {
    const float* x      = (const float*)d_in[0];
    const float* eWih0  = (const float*)d_in[1];
    const float* eWhh0  = (const float*)d_in[2];
    const float* ebih0  = (const float*)d_in[3];
    const float* ebhh0  = (const float*)d_in[4];
    const float* eWih1  = (const float*)d_in[5];
    const float* eWhh1  = (const float*)d_in[6];
    const float* ebih1  = (const float*)d_in[7];
    const float* ebhh1  = (const float*)d_in[8];
    const float* dWih0  = (const float*)d_in[9];
    const float* dWhh0  = (const float*)d_in[10];
    const float* dbih0  = (const float*)d_in[11];
    const float* dbhh0  = (const float*)d_in[12];
    const float* dWih1  = (const float*)d_in[13];
    const float* dWhh1  = (const float*)d_in[14];
    const float* dbih1  = (const float*)d_in[15];
    const float* dbhh1  = (const float*)d_in[16];
    const float* fcin_w = (const float*)d_in[17];
    const float* fcin_b = (const float*)d_in[18];
    const float* fcout_w= (const float*)d_in[19];
    const float* fcout_b= (const float*)d_in[20];
    float* out = (float*)d_out;

    char* base = (char*)d_ws;
    size_t off = 0;
    auto alloc = [&](size_t bytes) -> void* {
        void* r = base + off;
        off += (bytes + 255) & ~(size_t)255;
        return r;
    };
    bf16* wWih0e = (bf16*)alloc((size_t)H3 * 128 * 2);     // K-padded 96->128
    bf16* wWhh0e = (bf16*)alloc((size_t)H3 * Hh * 2);
    bf16* wWih1e = (bf16*)alloc((size_t)H3 * Hh * 2);
    bf16* wWhh1e = (bf16*)alloc((size_t)H3 * Hh * 2);
    bf16* wWhh0d = (bf16*)alloc((size_t)H3 * Hh * 2);
    bf16* wWih1d = (bf16*)alloc((size_t)H3 * Hh * 2);
    bf16* wWhh1d = (bf16*)alloc((size_t)H3 * Hh * 2);
    bf16* wWih0d = (bf16*)alloc((size_t)H3 * Hh * 2);
    bf16* fcinT  = (bf16*)alloc((size_t)128 * Hh * 2);     // fcin_w^T padded
    bf16* wWcomb = (bf16*)alloc((size_t)H3 * 128 * 2);     // dWih0 @ fcin_w, K-pad
    float* bcomb = (float*)alloc((size_t)H3 * 4);
    bf16* wfcout = (bf16*)alloc((size_t)128 * Hh * 2);     // padded 96->128 rows
    float* zbias = (float*)alloc((size_t)128 * 4);
    bf16* xbT    = (bf16*)alloc((size_t)Tt * Bsz * 128 * 2);
    bf16* gi1_p  = (bf16*)alloc((size_t)Bsz * H3 * 2);
    bf16* gh1_p  = (bf16*)alloc((size_t)Bsz * H3 * 2);
    bf16* gh0_p  = (bf16*)alloc((size_t)Bsz * H3 * 2);
    bf16* gi0_p  = (bf16*)alloc((size_t)Bsz * H3 * 2);
    float* h0    = (float*)alloc((size_t)Bsz * Hh * 4);
    float* h1    = (float*)alloc((size_t)Bsz * Hh * 4);
    bf16* h0b    = (bf16*)alloc((size_t)Bsz * Hh * 2);
    bf16* h1b    = (bf16*)alloc((size_t)Bsz * Hh * 2);
    float* gfc   = (float*)alloc((size_t)8 * Bsz * Ii * 4);
    float* fbuf0 = (float*)alloc((size_t)Bsz * Ii * 4);
    float* fbuf1 = (float*)alloc((size_t)Bsz * Ii * 4);
    bf16* frameb = (bf16*)alloc((size_t)Bsz * 128 * 2);    // row stride 128
    unsigned long long* tab = (unsigned long long*)alloc(8 * 8 * 8);
    if (off > ws_size) return;

    auto cvt = [&](const float* s, bf16* d, int n) {
        cvt_k<<<dim3((n + 255) / 256), dim3(256), 0, stream>>>(s, d, n);
    };
    cvtpad_k<<<dim3((H3 * 128 + 255) / 256), dim3(256), 0, stream>>>(eWih0, wWih0e, H3);
    cvt(eWhh0, wWhh0e, H3 * Hh);
    cvt(eWih1, wWih1e, H3 * Hh);
    cvt(eWhh1, wWhh1e, H3 * Hh);
    cvt(dWih0, wWih0d, H3 * Hh);
    cvt(dWhh0, wWhh0d, H3 * Hh);
    cvt(dWih1, wWih1d, H3 * Hh);
    cvt(dWhh1, wWhh1d, H3 * Hh);
    (void)hipMemsetAsync(wfcout, 0, (size_t)128 * Hh * 2, stream);
    (void)hipMemsetAsync(wWcomb, 0, (size_t)H3 * 128 * 2, stream);
    (void)hipMemsetAsync(zbias, 0, (size_t)128 * 4, stream);
    (void)hipMemsetAsync(frameb, 0, (size_t)Bsz * 128 * 2, stream);
    cvt(fcout_w, wfcout, Ii * Hh);
    // fc_in composition: Wcomb = dWih0 @ fcin_w (ldc=128) ; bcomb = dWih0@fcin_b + dbih0
    tposeFcin_k<<<dim3((128 * Hh + 255) / 256), dim3(256), 0, stream>>>(fcin_w, fcinT);
    gemm64<true><<<dim3(2, 48, 1), dim3(256), 0, stream>>>(
        wWih0d, fcinT, zbias, (void*)wWcomb, H3, Ii, Hh, Hh, Hh, 128);
    bcomb_k<<<dim3(H3), dim3(256), 0, stream>>>(dWih0, fcin_b, dbih0, bcomb);

    tpose_k<<<dim3((Tt * Bsz * 128 + 255) / 256), dim3(256), 0, stream>>>(x, xbT);
    prefix_k<<<dim3((Bsz * Pp * Ii + 255) / 256), dim3(256), 0, stream>>>(x, out);
    finit_k<<<dim3((Bsz * Ii + 255) / 256), dim3(256), 0, stream>>>(x, fbuf0, frameb);
    (void)hipMemsetAsync(h0, 0, (size_t)Bsz * Hh * 4, stream);
    (void)hipMemsetAsync(h1, 0, (size_t)Bsz * Hh * 4, stream);
    (void)hipMemsetAsync(h0b, 0, (size_t)Bsz * Hh * 2, stream);
    (void)hipMemsetAsync(h1b, 0, (size_t)Bsz * Hh * 2, stream);

    // descriptor table (8 slots):
    // 0: enc gi1   1: enc gh1   2: enc gh0   3: enc gi0 (A=extra xbT+t, K=128)
    // 4: dec gi1   5: dec gh1   6: dec gh0   7: dec gi0 (frameb @ Wcomb, K=128)
    wdesc_k<<<1, 64, 0, stream>>>(tab + 0 * 8, h0b, wWih1e, ebih1, gi1_p, Hh, Hh);
    wdesc_k<<<1, 64, 0, stream>>>(tab + 1 * 8, h1b, wWhh1e, ebhh1, gh1_p, Hh, Hh);
    wdesc_k<<<1, 64, 0, stream>>>(tab + 2 * 8, h0b, wWhh0e, ebhh0, gh0_p, Hh, Hh);
    wdesc_k<<<1, 64, 0, stream>>>(tab + 3 * 8, nullptr, wWih0e, ebih0, gi0_p, 128, 128);
    wdesc_k<<<1, 64, 0, stream>>>(tab + 4 * 8, h0b, wWih1d, dbih1, gi1_p, Hh, Hh);
    wdesc_k<<<1, 64, 0, stream>>>(tab + 5 * 8, h1b, wWhh1d, dbhh1, gh1_p, Hh, Hh);
    wdesc_k<<<1, 64, 0, stream>>>(tab + 6 * 8, h0b, wWhh0d, dbhh0, gh0_p, Hh, Hh);
    wdesc_k<<<1, 64, 0, stream>>>(tab + 7 * 8, frameb, wWcomb, bcomb, gi0_p, 128, 128);

    // ---- encoder ----
    // init: gh0 (h=0) + gi0(t=0)  -> h0(step 0)
    gemm_tab<<<dim3(384), dim3(256), 0, stream>>>(tab, 2, 2, xbT);
    gru_cell_k<<<dim3(1024), dim3(256), 0, stream>>>(gi0_p, gh0_p, h0, h0b);
    for (int i = 0; i < Pp; ++i) {
        if (i < Pp - 1) {
            gemm_tab<<<dim3(768), dim3(256), 0, stream>>>(
                tab, 0, 4, xbT + (size_t)(i + 1) * Bsz * 128);
            gru_cell2_k<<<dim3(2048), dim3(256), 0, stream>>>(
                gi1_p, gh1_p, h1, h1b, gi0_p, gh0_p, h0, h0b);
        } else {
            gemm_tab<<<dim3(384), dim3(256), 0, stream>>>(tab, 0, 2, xbT);
            gru_cell_k<<<dim3(1024), dim3(256), 0, stream>>>(gi1_p, gh1_p, h1, h1b);
        }
    }

    // ---- decoder ----
    // pre: gh0 (from h_enc0) + gi0 (from frame_0 via Wcomb @ frameb) -> hd0(step 0)
    gemm_tab<<<dim3(384), dim3(256), 0, stream>>>(tab, 6, 2, xbT);
    gru_cell_k<<<dim3(1024), dim3(256), 0, stream>>>(gi0_p, gh0_p, h0, h0b);
    for (int t = 0; t < Tt - Pp; ++t) {
        const bool last = (t == Tt - Pp - 1);
        if (!last) {
            gemm_tab<<<dim3(576), dim3(256), 0, stream>>>(tab, 4, 3, xbT);
        } else {
            gemm_tab<<<dim3(384), dim3(256), 0, stream>>>(tab, 4, 2, xbT);
        }
        gru_cell_k<<<dim3(1024), dim3(256), 0, stream>>>(gi1_p, gh1_p, h1, h1b);
        gemm64<false><<<dim3(2, 16, 8), dim3(256), 0, stream>>>(
            h1b, wfcout, fcout_b, (void*)gfc, Bsz, Ii, Hh, Hh / 8, Hh, Ii);
        // fused: frame(t+1) = frame(t) + sum(partials); out rows; gi0(t+1)
        fuse_fg_k<<<dim3(384), dim3(256), 0, stream>>>(
            gfc, (t & 1) ? fbuf1 : fbuf0, (t & 1) ? fbuf0 : fbuf1,
            out + (size_t)(Pp + t) * Ii, wWcomb, bcomb, gi0_p);
        if (!last) {
            gru_cell_k<<<dim3(1024), dim3(256), 0, stream>>>(gi0_p, gh0_p, h0, h0b);
        }
    }
}